// Round 5
// baseline (54.845 us; speedup 1.0000x reference)
//
#include <hip/hip_runtime.h>
#include <hip/hip_bf16.h>

namespace {

constexpr int kB = 2;
constexpr int kL = 2048;
constexpr int kD = 1024;
constexpr int kN = 16;
constexpr int kTPB = 256;
constexpr int kDPT = 2;                       // d-values per thread
constexpr int kNDBLK2 = kD / (kTPB * kDPT);   // 2 blocks cover D
constexpr int kBD = kB * kD;                  // 2048
constexpr int kBDN = kBD * kN;                // 32768
constexpr float kLog2e = 1.4426950408889634f;

__device__ __forceinline__ float ex2(float v) {
  return __builtin_amdgcn_exp2f(v);
}

// a[n] = e1^(n+1), log-depth (4 squares + 11 muls)
__device__ __forceinline__ void build_pows(float e1, float* a) {
  const float p2 = e1 * e1;
  const float p4 = p2 * p2;
  const float p8 = p4 * p4;
  a[0] = e1;      a[1] = p2;      a[2] = p2 * e1;  a[3] = p4;
  a[4] = p4 * e1; a[5] = p4 * p2; a[6] = p4 * a[2]; a[7] = p8;
  a[8] = p8 * e1; a[9] = p8 * p2; a[10] = p8 * a[2]; a[11] = p8 * p4;
  a[12] = p8 * a[4]; a[13] = p8 * a[5]; a[14] = p8 * a[6]; a[15] = p8 * p8;
}

// fast iff Alog[d][n] == Alog[d][0] + ln(n+1) for both owned d (then
// a_n = e1^(n+1)). Scoped so no AnL array stays live in the fast loop.
__device__ __forceinline__ bool fast_check(const float* __restrict__ Alog,
                                           int d0) {
  const float a00 = Alog[(size_t)d0 * kN];
  const float a10 = Alog[(size_t)(d0 + 1) * kN];
  bool f = true;
#pragma unroll
  for (int n = 1; n < kN; ++n) {
    const float lg = logf((float)(n + 1));  // compile-time constant
    f = f && (fabsf(Alog[(size_t)d0 * kN + n] - a00 - lg) <= 1e-3f);
    f = f && (fabsf(Alog[(size_t)(d0 + 1) * kN + n] - a10 - lg) <= 1e-3f);
  }
  return __all(f);
}

// Workspace layout: WS/WI[c][n][bd] (lane-coalesced float2 in bd),
// SDT[c][bd].

// ---------------- Phase 1: per-chunk local scan ----------------
template <int C>
__global__ __launch_bounds__(kTPB) void ssm_phase1(
    const float* __restrict__ x, const float* __restrict__ dt,
    const float* __restrict__ Bin, const float* __restrict__ Alog,
    float* __restrict__ WS, float* __restrict__ SDT) {
  constexpr int LC = kL / C;
  const int bid = blockIdx.x;
  const int c = bid % C;
  const int r = bid / C;
  const int dblk = r % kNDBLK2;
  const int b = r / kNDBLK2;
  const int tid = threadIdx.x;
  const int d0 = dblk * (kTPB * kDPT) + tid * kDPT;
  const int t0 = c * LC;

  const bool fast = fast_check(Alog, d0);

  const float* xp = x + ((size_t)b * kL + t0) * kD + d0;
  const float* dp = dt + ((size_t)b * kL + t0) * kD + d0;
  const float* bp = Bin + ((size_t)b * kL + t0) * kN;

  float s0[kN], s1[kN];
#pragma unroll
  for (int n = 0; n < kN; ++n) { s0[n] = 0.f; s1[n] = 0.f; }
  float sdt0 = 0.f, sdt1 = 0.f;

  if (fast) {
    const float A00 = -__expf(Alog[(size_t)d0 * kN]) * kLog2e;
    const float A01 = -__expf(Alog[(size_t)(d0 + 1) * kN]) * kLog2e;
#pragma unroll 4
    for (int tt = 0; tt < LC; ++tt) {
      const float2 dtv = *reinterpret_cast<const float2*>(dp + (size_t)tt * kD);
      const float2 xv = *reinterpret_cast<const float2*>(xp + (size_t)tt * kD);
      sdt0 += dtv.x;
      sdt1 += dtv.y;
      const float dtx0 = dtv.x * xv.x;
      const float dtx1 = dtv.y * xv.y;
      float a0[kN], a1[kN];
      build_pows(ex2(dtv.x * A00), a0);
      build_pows(ex2(dtv.y * A01), a1);
#pragma unroll
      for (int n = 0; n < kN; ++n) {
        const float bn = bp[tt * kN + n];  // wave-uniform -> scalar load
        s0[n] = fmaf(a0[n], s0[n], dtx0 * bn);
        s1[n] = fmaf(a1[n], s1[n], dtx1 * bn);
      }
    }
  } else {
    float An0[kN], An1[kN];
#pragma unroll
    for (int n = 0; n < kN; ++n) {
      An0[n] = -__expf(Alog[(size_t)d0 * kN + n]) * kLog2e;
      An1[n] = -__expf(Alog[(size_t)(d0 + 1) * kN + n]) * kLog2e;
    }
#pragma unroll 2
    for (int tt = 0; tt < LC; ++tt) {
      const float2 dtv = *reinterpret_cast<const float2*>(dp + (size_t)tt * kD);
      const float2 xv = *reinterpret_cast<const float2*>(xp + (size_t)tt * kD);
      sdt0 += dtv.x;
      sdt1 += dtv.y;
      const float dtx0 = dtv.x * xv.x;
      const float dtx1 = dtv.y * xv.y;
#pragma unroll
      for (int n = 0; n < kN; ++n) {
        const float bn = bp[tt * kN + n];
        s0[n] = fmaf(ex2(dtv.x * An0[n]), s0[n], dtx0 * bn);
        s1[n] = fmaf(ex2(dtv.y * An1[n]), s1[n], dtx1 * bn);
      }
    }
  }

  const size_t bd = (size_t)b * kD + d0;
#pragma unroll
  for (int n = 0; n < kN; ++n)
    *reinterpret_cast<float2*>(WS + (size_t)c * kBDN + (size_t)n * kBD + bd) =
        make_float2(s0[n], s1[n]);
  *reinterpret_cast<float2*>(SDT + (size_t)c * kBD + bd) =
      make_float2(sdt0, sdt1);
}

// ---------------- Phase 2: scan across chunk aggregates ----------------
template <int C>
__global__ __launch_bounds__(128) void ssm_phase2(
    const float* __restrict__ WS, const float* __restrict__ SDT,
    const float* __restrict__ Alog, float* __restrict__ WI) {
  const int i = blockIdx.x * 128 + threadIdx.x;  // < kBDN
  const int n = i >> 11;          // n-major: lanes contiguous in bd
  const int bd = i & (kBD - 1);
  const int d = bd & (kD - 1);
  const float An = -__expf(Alog[(size_t)d * kN + n]) * kLog2e;
  float carry = 0.f;
#pragma unroll 8
  for (int c = 0; c < C; ++c) {
    const size_t idx = (size_t)c * kBDN + (size_t)n * kBD + bd;
    const float a = ex2(An * SDT[(size_t)c * kBD + bd]);
    WI[idx] = carry;
    carry = fmaf(a, carry, WS[idx]);
  }
}

// ---------------- Phase 3: replay with true init, fused epilogue ----------------
template <int C>
__global__ __launch_bounds__(kTPB) void ssm_phase3(
    const float* __restrict__ x, const float* __restrict__ dt,
    const float* __restrict__ Bin, const float* __restrict__ Cin,
    const float* __restrict__ Alog, const float* __restrict__ Dp,
    const float* __restrict__ WI, float* __restrict__ y) {
  constexpr int LC = kL / C;
  const int bid = blockIdx.x;
  const int c = bid % C;
  const int r = bid / C;
  const int dblk = r % kNDBLK2;
  const int b = r / kNDBLK2;
  const int tid = threadIdx.x;
  const int d0 = dblk * (kTPB * kDPT) + tid * kDPT;
  const int t0 = c * LC;

  const bool fast = fast_check(Alog, d0);

  float s0[kN], s1[kN];
  const size_t bd = (size_t)b * kD + d0;
#pragma unroll
  for (int n = 0; n < kN; ++n) {
    const float2 v = *reinterpret_cast<const float2*>(
        WI + (size_t)c * kBDN + (size_t)n * kBD + bd);
    s0[n] = v.x;
    s1[n] = v.y;
  }

  const float2 Dv = *reinterpret_cast<const float2*>(Dp + d0);
  const float* xp = x + ((size_t)b * kL + t0) * kD + d0;
  const float* dp = dt + ((size_t)b * kL + t0) * kD + d0;
  const float* bp = Bin + ((size_t)b * kL + t0) * kN;
  const float* cp = Cin + ((size_t)b * kL + t0) * kN;
  float* yp = y + ((size_t)b * kL + t0) * kD + d0;

  if (fast) {
    const float A00 = -__expf(Alog[(size_t)d0 * kN]) * kLog2e;
    const float A01 = -__expf(Alog[(size_t)(d0 + 1) * kN]) * kLog2e;
#pragma unroll 4
    for (int tt = 0; tt < LC; ++tt) {
      const float2 dtv = *reinterpret_cast<const float2*>(dp + (size_t)tt * kD);
      const float2 xv = *reinterpret_cast<const float2*>(xp + (size_t)tt * kD);
      const float dtx0 = dtv.x * xv.x;
      const float dtx1 = dtv.y * xv.y;
      float a0[kN], a1[kN];
      build_pows(ex2(dtv.x * A00), a0);
      build_pows(ex2(dtv.y * A01), a1);
      float acc0 = 0.f, acc1 = 0.f;
#pragma unroll
      for (int n = 0; n < kN; ++n) {
        const float bn = bp[tt * kN + n];  // scalar
        const float cn = cp[tt * kN + n];  // scalar
        s0[n] = fmaf(a0[n], s0[n], dtx0 * bn);
        s1[n] = fmaf(a1[n], s1[n], dtx1 * bn);
        acc0 = fmaf(s0[n], cn, acc0);
        acc1 = fmaf(s1[n], cn, acc1);
      }
      *reinterpret_cast<float2*>(yp + (size_t)tt * kD) =
          make_float2(fmaf(xv.x, Dv.x, acc0), fmaf(xv.y, Dv.y, acc1));
    }
  } else {
    float An0[kN], An1[kN];
#pragma unroll
    for (int n = 0; n < kN; ++n) {
      An0[n] = -__expf(Alog[(size_t)d0 * kN + n]) * kLog2e;
      An1[n] = -__expf(Alog[(size_t)(d0 + 1) * kN + n]) * kLog2e;
    }
#pragma unroll 2
    for (int tt = 0; tt < LC; ++tt) {
      const float2 dtv = *reinterpret_cast<const float2*>(dp + (size_t)tt * kD);
      const float2 xv = *reinterpret_cast<const float2*>(xp + (size_t)tt * kD);
      const float dtx0 = dtv.x * xv.x;
      const float dtx1 = dtv.y * xv.y;
      float acc0 = 0.f, acc1 = 0.f;
#pragma unroll
      for (int n = 0; n < kN; ++n) {
        const float bn = bp[tt * kN + n];
        const float cn = cp[tt * kN + n];
        s0[n] = fmaf(ex2(dtv.x * An0[n]), s0[n], dtx0 * bn);
        s1[n] = fmaf(ex2(dtv.y * An1[n]), s1[n], dtx1 * bn);
        acc0 = fmaf(s0[n], cn, acc0);
        acc1 = fmaf(s1[n], cn, acc1);
      }
      *reinterpret_cast<float2*>(yp + (size_t)tt * kD) =
          make_float2(fmaf(xv.x, Dv.x, acc0), fmaf(xv.y, Dv.y, acc1));
    }
  }
}

// ---------------- Fallback: fully sequential (no workspace) ----------------
__global__ __launch_bounds__(256) void ssm_seq(
    const float* __restrict__ x, const float* __restrict__ dt,
    const float* __restrict__ Bin, const float* __restrict__ Cin,
    const float* __restrict__ Alog, const float* __restrict__ Dp,
    float* __restrict__ y) {
  const int gid = blockIdx.x * 256 + threadIdx.x;
  if (gid >= kB * kD) return;
  const int b = gid / kD;
  const int d = gid % kD;

  float AnL[kN];
  const float* al = Alog + (size_t)d * kN;
#pragma unroll
  for (int n = 0; n < kN; ++n) AnL[n] = -__expf(al[n]) * kLog2e;

  float s[kN];
#pragma unroll
  for (int n = 0; n < kN; ++n) s[n] = 0.f;
  const float Dv = Dp[d];

  const float* xp = x + (size_t)b * kL * kD + d;
  const float* dp = dt + (size_t)b * kL * kD + d;
  const float* bp = Bin + (size_t)b * kL * kN;
  const float* cp = Cin + (size_t)b * kL * kN;
  float* yp = y + (size_t)b * kL * kD + d;

  for (int t = 0; t < kL; ++t) {
    const float dtv = dp[(size_t)t * kD];
    const float xv = xp[(size_t)t * kD];
    const float dtx = dtv * xv;
    float acc = 0.f;
#pragma unroll
    for (int n = 0; n < kN; ++n) {
      const float a = ex2(dtv * AnL[n]);
      s[n] = fmaf(a, s[n], dtx * bp[t * kN + n]);
      acc = fmaf(s[n], cp[t * kN + n], acc);
    }
    yp[(size_t)t * kD] = fmaf(xv, Dv, acc);
  }
}

template <int C>
void launch_chunked(const float* x, const float* dtp, const float* Bin,
                    const float* Cin, const float* Alog, const float* Dp,
                    float* y, float* ws, hipStream_t stream) {
  float* WS = ws;                          // C * kBDN
  float* SDT = WS + (size_t)C * kBDN;      // C * kBD
  float* WI = SDT + (size_t)C * kBD;       // C * kBDN
  const int g = C * kB * kNDBLK2;
  ssm_phase1<C><<<g, kTPB, 0, stream>>>(x, dtp, Bin, Alog, WS, SDT);
  ssm_phase2<C><<<kBDN / 128, 128, 0, stream>>>(WS, SDT, Alog, WI);
  ssm_phase3<C><<<g, kTPB, 0, stream>>>(x, dtp, Bin, Cin, Alog, Dp, WI, y);
}

}  // namespace

extern "C" void kernel_launch(void* const* d_in, const int* in_sizes, int n_in,
                              void* d_out, int out_size, void* d_ws, size_t ws_size,
                              hipStream_t stream) {
  const float* x    = (const float*)d_in[0];
  const float* dtp  = (const float*)d_in[1];
  const float* Bin  = (const float*)d_in[2];
  const float* Cin  = (const float*)d_in[3];
  const float* Alog = (const float*)d_in[4];
  const float* Dp   = (const float*)d_in[5];
  float* y = (float*)d_out;
  float* ws = (float*)d_ws;

  auto need = [](int C) {
    return (size_t)(2 * C * kBDN + C * kBD) * sizeof(float);
  };

  if (ws_size >= need(128)) {
    launch_chunked<128>(x, dtp, Bin, Cin, Alog, Dp, y, ws, stream);
  } else if (ws_size >= need(64)) {
    launch_chunked<64>(x, dtp, Bin, Cin, Alog, Dp, y, ws, stream);
  } else if (ws_size >= need(16)) {
    launch_chunked<16>(x, dtp, Bin, Cin, Alog, Dp, y, ws, stream);
  } else {
    ssm_seq<<<(kB * kD + 255) / 256, 256, 0, stream>>>(x, dtp, Bin, Cin, Alog,
                                                       Dp, y);
  }
}

// Round 6
// 42.142 us; speedup vs baseline: 1.3014x; 1.3014x over previous
//
#include <hip/hip_runtime.h>
#include <hip/hip_bf16.h>
#include <hip/hip_fp16.h>

namespace {

constexpr int kB = 2;
constexpr int kL = 2048;
constexpr int kD = 1024;
constexpr int kN = 16;
constexpr int kNH = kN / 2;                 // half2 pairs
constexpr int kTPB = 256;
constexpr int kNDBLK = kD / kTPB;           // 4 blocks cover D
constexpr int kBD = kB * kD;                // 2048
constexpr int kBDN = kBD * kN;              // 32768
constexpr float kLog2e = 1.4426950408889634f;

__device__ __forceinline__ float ex2(float v) {
  return __builtin_amdgcn_exp2f(v);
}

// a[n] = e1^(n+1), log-depth (4 squares + 11 muls)
__device__ __forceinline__ void build_pows(float e1, float* a) {
  const float p2 = e1 * e1;
  const float p4 = p2 * p2;
  const float p8 = p4 * p4;
  a[0] = e1;      a[1] = p2;      a[2] = p2 * e1;  a[3] = p4;
  a[4] = p4 * e1; a[5] = p4 * p2; a[6] = p4 * a[2]; a[7] = p8;
  a[8] = p8 * e1; a[9] = p8 * p2; a[10] = p8 * a[2]; a[11] = p8 * p4;
  a[12] = p8 * a[4]; a[13] = p8 * a[5]; a[14] = p8 * a[6]; a[15] = p8 * p8;
}

// Workspace layout:
//   WSH/WIH: __half2[C][kNH][kBD]  (chunk finals / chunk true inits)
//   SDT:     float  [C][kBD]       (chunk dt-sums)

// ---------------- Phase 1: per-chunk local scan ----------------
template <int C>
__global__ __launch_bounds__(kTPB) void ssm_phase1(
    const float* __restrict__ x, const float* __restrict__ dt,
    const float* __restrict__ Bin, const float* __restrict__ Alog,
    __half2* __restrict__ WSH, float* __restrict__ SDT) {
  constexpr int LC = kL / C;
  const int bid = blockIdx.x;
  const int c = bid % C;
  const int r = bid / C;
  const int dblk = r % kNDBLK;
  const int b = r / kNDBLK;
  const int d = dblk * kTPB + threadIdx.x;
  const int t0 = c * LC;

  float AnL[kN];
  const float* al = Alog + (size_t)d * kN;
#pragma unroll
  for (int n = 0; n < kN; ++n) AnL[n] = -__expf(al[n]) * kLog2e;
  bool fast = true;
#pragma unroll
  for (int n = 1; n < kN; ++n)
    fast = fast && (fabsf(AnL[n] - (float)(n + 1) * AnL[0]) <=
                    1e-4f * fabsf(AnL[n]));

  float s[kN];
#pragma unroll
  for (int n = 0; n < kN; ++n) s[n] = 0.f;
  float sdt = 0.f;

  const float* xp = x + ((size_t)b * kL + t0) * kD + d;
  const float* dp = dt + ((size_t)b * kL + t0) * kD + d;
  const float* bp = Bin + ((size_t)b * kL + t0) * kN;

  if (fast) {
    const float A0 = AnL[0];
#pragma unroll 4
    for (int tt = 0; tt < LC; ++tt) {
      const float dtv = dp[(size_t)tt * kD];
      const float xv = xp[(size_t)tt * kD];
      sdt += dtv;
      const float dtx = dtv * xv;
      float a[kN];
      build_pows(ex2(dtv * A0), a);
#pragma unroll
      for (int n = 0; n < kN; ++n)
        s[n] = fmaf(a[n], s[n], dtx * bp[tt * kN + n]);  // bp: scalar load
    }
  } else {
#pragma unroll 2
    for (int tt = 0; tt < LC; ++tt) {
      const float dtv = dp[(size_t)tt * kD];
      const float xv = xp[(size_t)tt * kD];
      sdt += dtv;
      const float dtx = dtv * xv;
#pragma unroll
      for (int n = 0; n < kN; ++n)
        s[n] = fmaf(ex2(dtv * AnL[n]), s[n], dtx * bp[tt * kN + n]);
    }
  }

  const size_t bd = (size_t)b * kD + d;
  const size_t base = (size_t)c * kNH * kBD + bd;
#pragma unroll
  for (int q = 0; q < kNH; ++q)
    WSH[base + (size_t)q * kBD] =
        __float22half2_rn(make_float2(s[2 * q], s[2 * q + 1]));
  SDT[(size_t)c * kBD + bd] = sdt;
}

// ---------------- Phase 2: scan across chunk aggregates ----------------
template <int C>
__global__ __launch_bounds__(128) void ssm_phase2(
    const __half2* __restrict__ WSH, const float* __restrict__ SDT,
    const float* __restrict__ Alog, __half2* __restrict__ WIH) {
  const int j = blockIdx.x * 128 + threadIdx.x;  // < kBDN/2
  const int q = j >> 11;                         // n-pair, lanes contiguous bd
  const int bd = j & (kBD - 1);
  const int d = bd & (kD - 1);
  const float An0 = -__expf(Alog[(size_t)d * kN + 2 * q]) * kLog2e;
  const float An1 = -__expf(Alog[(size_t)d * kN + 2 * q + 1]) * kLog2e;
  float c0 = 0.f, c1 = 0.f;
#pragma unroll 4
  for (int c = 0; c < C; ++c) {
    const float sdt = SDT[(size_t)c * kBD + bd];
    const size_t idx = ((size_t)c * kNH + q) * kBD + bd;
    WIH[idx] = __float22half2_rn(make_float2(c0, c1));
    const float2 sf = __half22float2(WSH[idx]);
    c0 = fmaf(ex2(An0 * sdt), c0, sf.x);
    c1 = fmaf(ex2(An1 * sdt), c1, sf.y);
  }
}

// ---------------- Phase 3: replay with true init, fused epilogue ----------------
template <int C>
__global__ __launch_bounds__(kTPB) void ssm_phase3(
    const float* __restrict__ x, const float* __restrict__ dt,
    const float* __restrict__ Bin, const float* __restrict__ Cin,
    const float* __restrict__ Alog, const float* __restrict__ Dp,
    const __half2* __restrict__ WIH, float* __restrict__ y) {
  constexpr int LC = kL / C;
  const int bid = blockIdx.x;
  const int c = bid % C;
  const int r = bid / C;
  const int dblk = r % kNDBLK;
  const int b = r / kNDBLK;
  const int d = dblk * kTPB + threadIdx.x;
  const int t0 = c * LC;

  float AnL[kN];
  const float* al = Alog + (size_t)d * kN;
#pragma unroll
  for (int n = 0; n < kN; ++n) AnL[n] = -__expf(al[n]) * kLog2e;
  bool fast = true;
#pragma unroll
  for (int n = 1; n < kN; ++n)
    fast = fast && (fabsf(AnL[n] - (float)(n + 1) * AnL[0]) <=
                    1e-4f * fabsf(AnL[n]));

  float s[kN];
  const size_t bd = (size_t)b * kD + d;
  {
    const size_t base = (size_t)c * kNH * kBD + bd;
#pragma unroll
    for (int q = 0; q < kNH; ++q) {
      const float2 v = __half22float2(WIH[base + (size_t)q * kBD]);
      s[2 * q] = v.x;
      s[2 * q + 1] = v.y;
    }
  }

  const float Dv = Dp[d];
  const float* xp = x + ((size_t)b * kL + t0) * kD + d;
  const float* dp = dt + ((size_t)b * kL + t0) * kD + d;
  const float* bp = Bin + ((size_t)b * kL + t0) * kN;
  const float* cp = Cin + ((size_t)b * kL + t0) * kN;
  float* yp = y + ((size_t)b * kL + t0) * kD + d;

  if (fast) {
    const float A0 = AnL[0];
#pragma unroll 4
    for (int tt = 0; tt < LC; ++tt) {
      const float dtv = dp[(size_t)tt * kD];
      const float xv = xp[(size_t)tt * kD];
      const float dtx = dtv * xv;
      float a[kN];
      build_pows(ex2(dtv * A0), a);
      float acc = 0.f;
#pragma unroll
      for (int n = 0; n < kN; ++n) {
        s[n] = fmaf(a[n], s[n], dtx * bp[tt * kN + n]);
        acc = fmaf(s[n], cp[tt * kN + n], acc);
      }
      __builtin_nontemporal_store(fmaf(xv, Dv, acc), yp + (size_t)tt * kD);
    }
  } else {
#pragma unroll 2
    for (int tt = 0; tt < LC; ++tt) {
      const float dtv = dp[(size_t)tt * kD];
      const float xv = xp[(size_t)tt * kD];
      const float dtx = dtv * xv;
      float acc = 0.f;
#pragma unroll
      for (int n = 0; n < kN; ++n) {
        s[n] = fmaf(ex2(dtv * AnL[n]), s[n], dtx * bp[tt * kN + n]);
        acc = fmaf(s[n], cp[tt * kN + n], acc);
      }
      __builtin_nontemporal_store(fmaf(xv, Dv, acc), yp + (size_t)tt * kD);
    }
  }
}

// ---------------- Fallback: fully sequential (no workspace) ----------------
__global__ __launch_bounds__(256) void ssm_seq(
    const float* __restrict__ x, const float* __restrict__ dt,
    const float* __restrict__ Bin, const float* __restrict__ Cin,
    const float* __restrict__ Alog, const float* __restrict__ Dp,
    float* __restrict__ y) {
  const int gid = blockIdx.x * 256 + threadIdx.x;
  if (gid >= kB * kD) return;
  const int b = gid / kD;
  const int d = gid % kD;

  float AnL[kN];
  const float* al = Alog + (size_t)d * kN;
#pragma unroll
  for (int n = 0; n < kN; ++n) AnL[n] = -__expf(al[n]) * kLog2e;

  float s[kN];
#pragma unroll
  for (int n = 0; n < kN; ++n) s[n] = 0.f;
  const float Dv = Dp[d];

  const float* xp = x + (size_t)b * kL * kD + d;
  const float* dp = dt + (size_t)b * kL * kD + d;
  const float* bp = Bin + (size_t)b * kL * kN;
  const float* cp = Cin + (size_t)b * kL * kN;
  float* yp = y + (size_t)b * kL * kD + d;

  for (int t = 0; t < kL; ++t) {
    const float dtv = dp[(size_t)t * kD];
    const float xv = xp[(size_t)t * kD];
    const float dtx = dtv * xv;
    float acc = 0.f;
#pragma unroll
    for (int n = 0; n < kN; ++n) {
      const float a = ex2(dtv * AnL[n]);
      s[n] = fmaf(a, s[n], dtx * bp[t * kN + n]);
      acc = fmaf(s[n], cp[t * kN + n], acc);
    }
    yp[(size_t)t * kD] = fmaf(xv, Dv, acc);
  }
}

template <int C>
void launch_chunked(const float* x, const float* dtp, const float* Bin,
                    const float* Cin, const float* Alog, const float* Dp,
                    float* y, void* ws, hipStream_t stream) {
  __half2* WSH = reinterpret_cast<__half2*>(ws);            // C*kNH*kBD half2
  __half2* WIH = WSH + (size_t)C * kNH * kBD;               // C*kNH*kBD half2
  float* SDT = reinterpret_cast<float*>(WIH + (size_t)C * kNH * kBD);
  const int g = C * kB * kNDBLK;
  ssm_phase1<C><<<g, kTPB, 0, stream>>>(x, dtp, Bin, Alog, WSH, SDT);
  ssm_phase2<C><<<kBDN / 2 / 128, 128, 0, stream>>>(WSH, SDT, Alog, WIH);
  ssm_phase3<C><<<g, kTPB, 0, stream>>>(x, dtp, Bin, Cin, Alog, Dp, WIH, y);
}

}  // namespace

extern "C" void kernel_launch(void* const* d_in, const int* in_sizes, int n_in,
                              void* d_out, int out_size, void* d_ws, size_t ws_size,
                              hipStream_t stream) {
  const float* x    = (const float*)d_in[0];
  const float* dtp  = (const float*)d_in[1];
  const float* Bin  = (const float*)d_in[2];
  const float* Cin  = (const float*)d_in[3];
  const float* Alog = (const float*)d_in[4];
  const float* Dp   = (const float*)d_in[5];
  float* y = (float*)d_out;

  auto need = [](int C) {
    return (size_t)C * kNH * kBD * 2 * sizeof(__half2) +  // WSH + WIH
           (size_t)C * kBD * sizeof(float);               // SDT
  };

  if (ws_size >= need(128)) {
    launch_chunked<128>(x, dtp, Bin, Cin, Alog, Dp, y, d_ws, stream);
  } else if (ws_size >= need(64)) {
    launch_chunked<64>(x, dtp, Bin, Cin, Alog, Dp, y, d_ws, stream);
  } else if (ws_size >= need(16)) {
    launch_chunked<16>(x, dtp, Bin, Cin, Alog, Dp, y, d_ws, stream);
  } else {
    ssm_seq<<<(kB * kD + 255) / 256, 256, 0, stream>>>(x, dtp, Bin, Cin, Alog,
                                                       Dp, y);
  }
}